// Round 1
// baseline (309.842 us; speedup 1.0000x reference)
//
#include <hip/hip_runtime.h>
#include <hip/hip_bf16.h>
#include <cstdint>
#include <cstddef>

#define N_NODES 100000
#define N_EDGES 800000
#define IN_DIM 128
#define HID_DIM 256
#define OUT_DIM 128

typedef __attribute__((ext_vector_type(8))) short bf16x8;
typedef __attribute__((ext_vector_type(4))) float f32x4;

__device__ __forceinline__ unsigned short f32_to_bf16(float f) {
    __hip_bfloat16 b = __float2bfloat16(f);   // RNE
    return *reinterpret_cast<unsigned short*>(&b);
}
__device__ __forceinline__ float bf16_lo(uint32_t u) {
    uint32_t v = u << 16; return *reinterpret_cast<float*>(&v);
}
__device__ __forceinline__ float bf16_hi(uint32_t u) {
    uint32_t v = u & 0xffff0000u; return *reinterpret_cast<float*>(&v);
}

// ---------------------------------------------------------------------------
// CSR build. edge_index arrives int32 (harness converts integer inputs).
// rank_hist (1 int atomic + 1 float atomic per edge) -> scan (+dis) -> place
// (0 atomics, stores pre-normalized weight w*dis[src]*dis[dst]).
// ---------------------------------------------------------------------------
__global__ void rank_hist_kernel(const int* __restrict__ ei,
                                 const float* __restrict__ ew,
                                 int* __restrict__ cnt,
                                 float* __restrict__ deg,
                                 int* __restrict__ rank) {
    int e = blockIdx.x * 256 + threadIdx.x;
    if (e >= N_EDGES) return;
    int c = ei[N_EDGES + e];
    rank[e] = atomicAdd(&cnt[c], 1);
    atomicAdd(&deg[c], ew[e]);
}

__global__ void scan1_kernel(const int* __restrict__ in, int* __restrict__ out,
                             int* __restrict__ bsums, int n) {
    __shared__ int tmp[256];
    int t = threadIdx.x;
    int i = blockIdx.x * 256 + t;
    int v = (i < n) ? in[i] : 0;
    tmp[t] = v;
    __syncthreads();
    for (int off = 1; off < 256; off <<= 1) {
        int u = (t >= off) ? tmp[t - off] : 0;
        __syncthreads();
        tmp[t] += u;
        __syncthreads();
    }
    if (i < n) out[i] = tmp[t] - v;          // exclusive
    if (t == 255) bsums[blockIdx.x] = tmp[255];
}

__global__ void scan2_kernel(int* __restrict__ bsums, int nb) {
    __shared__ int tmp[512];
    int t = threadIdx.x;
    int v = (t < nb) ? bsums[t] : 0;
    tmp[t] = v;
    __syncthreads();
    for (int off = 1; off < 512; off <<= 1) {
        int u = (t >= off) ? tmp[t - off] : 0;
        __syncthreads();
        tmp[t] += u;
        __syncthreads();
    }
    if (t < nb) bsums[t] = tmp[t] - v;       // exclusive
}

// scan3 also finalizes dis = rsqrt(deg) (deg_dis pass eliminated).
__global__ void scan3_kernel(int* __restrict__ rowp, const int* __restrict__ bsums,
                             const float* __restrict__ deg, float* __restrict__ dis,
                             int n, int total) {
    int i = blockIdx.x * 256 + threadIdx.x;
    if (i == 0) rowp[n] = total;
    if (i >= n) return;
    rowp[i] += bsums[blockIdx.x];
    float d = deg[i];
    dis[i] = d > 0.f ? rsqrtf(d) : 0.f;
}

// place: no atomics — slot = rowp[col] + rank[e]. Stores the fully
// normalized edge weight so both aggregates skip the dis gathers.
__global__ void place_kernel(const int* __restrict__ ei,
                             const float* __restrict__ ew,
                             const int* __restrict__ rank,
                             const int* __restrict__ rowp,
                             const float* __restrict__ dis,
                             int2* __restrict__ pairs) {
    int e = blockIdx.x * 256 + threadIdx.x;
    if (e >= N_EDGES) return;
    int s = ei[e];
    int c = ei[N_EDGES + e];
    int pos = rowp[c] + rank[e];
    float wn = ew[e] * dis[s] * dis[c];      // dis is 400KB, L2-resident
    pairs[pos] = make_int2(s, __float_as_int(wn));
}

// ---------------------------------------------------------------------------
// Fused prep: xb = bf16(x); W1F/W2F = fragment-ordered bf16 weights.
// Fragment order: short index = ((((nh*2+wc)*4+ks)*4+nt)*64+lane)*8 + j
// so a wave's wf[nt] load is one coalesced dwordx4 at base + lane*16.
// Phase A (W1F): value = W1[kk][row], row = nh*128+wc*64+nt*16+fr,
//                kk = ks*32+fq*8+j.          (W1 is [128][256])
// Phase B (W2F): value = W2[kk][n],  n = wc*64+nt*16+fr,
//                kk = nh*128+ks*32+fq*8+j.   (W2 is [256][128])
// ---------------------------------------------------------------------------
__global__ void prep_kernel(const float* __restrict__ x, uint32_t* __restrict__ xb,
                            const float* __restrict__ W1, unsigned short* __restrict__ W1F,
                            const float* __restrict__ W2, unsigned short* __restrict__ W2F) {
    int b = blockIdx.x;
    if (b < 12500) {                                   // 12500*256*4 = 100000*128
        int i = b * 256 + threadIdx.x;
        float4 v = ((const float4*)x)[i];
        uint32_t lo = (uint32_t)f32_to_bf16(v.x) | ((uint32_t)f32_to_bf16(v.y) << 16);
        uint32_t hi = (uint32_t)f32_to_bf16(v.z) | ((uint32_t)f32_to_bf16(v.w) << 16);
        ((uint2*)xb)[i] = make_uint2(lo, hi);
    } else if (b < 12628) {                            // W1F: 32768 shorts
        int idx = (b - 12500) * 256 + threadIdx.x;
        int j = idx & 7, lane = (idx >> 3) & 63;
        int nt = (idx >> 9) & 3, ks = (idx >> 11) & 3;
        int wc = (idx >> 13) & 1, nh = (idx >> 14) & 1;
        int fr = lane & 15, fq = lane >> 4;
        int row = nh * 128 + wc * 64 + nt * 16 + fr;
        int kk = ks * 32 + fq * 8 + j;
        W1F[idx] = f32_to_bf16(W1[kk * HID_DIM + row]);
    } else {                                           // W2F: 32768 shorts
        int idx = (b - 12628) * 256 + threadIdx.x;
        int j = idx & 7, lane = (idx >> 3) & 63;
        int nt = (idx >> 9) & 3, ks = (idx >> 11) & 3;
        int wc = (idx >> 13) & 1, nh = (idx >> 14) & 1;
        int fr = lane & 15, fq = lane >> 4;
        int n = wc * 64 + nt * 16 + fr;
        int kk = nh * 128 + ks * 32 + fq * 8 + j;
        W2F[idx] = f32_to_bf16(W2[kk * OUT_DIM + n]);
    }
}

// ---------------------------------------------------------------------------
// Aggregation R8: 4 nodes per wave (16 lanes/node, uint4 = 8 bf16 dims/lane).
// Weight in pairs[].y is pre-normalized (w*dis[src]*dis[dst]) so the inner
// loop is gather+fma only. 16B/lane gathers double bytes-per-VMEM-instr and
// edges-in-flight vs the previous 32-lane/uint2 form (latency-bound fix).
// ---------------------------------------------------------------------------
__device__ __forceinline__ void acc_edge(float w, uint4 u, float* a) {
    a[0] += w * bf16_lo(u.x); a[1] += w * bf16_hi(u.x);
    a[2] += w * bf16_lo(u.y); a[3] += w * bf16_hi(u.y);
    a[4] += w * bf16_lo(u.z); a[5] += w * bf16_hi(u.z);
    a[6] += w * bf16_lo(u.w); a[7] += w * bf16_hi(u.w);
}

template <bool OUT_BF16>
__global__ void aggregate_kernel(const uint4* __restrict__ feat,
                                 const int* __restrict__ rowp,
                                 const int2* __restrict__ pairs,
                                 void* __restrict__ out_v,
                                 const float* __restrict__ bias) {
    int gtid = blockIdx.x * blockDim.x + threadIdx.x;
    int node = gtid >> 4;
    int lane = threadIdx.x & 15;
    if (node >= N_NODES) return;
    int beg = rowp[node], end = rowp[node + 1];
    float a[8] = {};

    int j = beg;
    for (; j + 4 <= end; j += 4) {
        int2 p[4]; uint4 u[4];
        #pragma unroll
        for (int q = 0; q < 4; ++q) p[q] = pairs[j + q];
        #pragma unroll
        for (int q = 0; q < 4; ++q) u[q] = feat[(size_t)p[q].x * 16 + lane];
        #pragma unroll
        for (int q = 0; q < 4; ++q) acc_edge(__int_as_float(p[q].y), u[q], a);
    }
    if (j + 2 <= end) {
        int2 p0 = pairs[j], p1 = pairs[j + 1];
        uint4 u0 = feat[(size_t)p0.x * 16 + lane];
        uint4 u1 = feat[(size_t)p1.x * 16 + lane];
        acc_edge(__int_as_float(p0.y), u0, a);
        acc_edge(__int_as_float(p1.y), u1, a);
        j += 2;
    }
    if (j < end) {
        int2 p0 = pairs[j];
        uint4 u0 = feat[(size_t)p0.x * 16 + lane];
        acc_edge(__int_as_float(p0.y), u0, a);
    }
    if (bias) {
        float4 b0 = ((const float4*)bias)[lane * 2];
        float4 b1 = ((const float4*)bias)[lane * 2 + 1];
        a[0] += b0.x; a[1] += b0.y; a[2] += b0.z; a[3] += b0.w;
        a[4] += b1.x; a[5] += b1.y; a[6] += b1.z; a[7] += b1.w;
    }
    if (OUT_BF16) {
        uint4 o;
        o.x = (uint32_t)f32_to_bf16(a[0]) | ((uint32_t)f32_to_bf16(a[1]) << 16);
        o.y = (uint32_t)f32_to_bf16(a[2]) | ((uint32_t)f32_to_bf16(a[3]) << 16);
        o.z = (uint32_t)f32_to_bf16(a[4]) | ((uint32_t)f32_to_bf16(a[5]) << 16);
        o.w = (uint32_t)f32_to_bf16(a[6]) | ((uint32_t)f32_to_bf16(a[7]) << 16);
        ((uint4*)out_v)[(size_t)node * 16 + lane] = o;
    } else {
        ((float4*)out_v)[(size_t)node * 32 + lane * 2] =
            make_float4(a[0], a[1], a[2], a[3]);
        ((float4*)out_v)[(size_t)node * 32 + lane * 2 + 1] =
            make_float4(a[4], a[5], a[6], a[7]);
    }
}

// ---------------------------------------------------------------------------
// Fused 2-layer GEMM: T = relu(A @ W1 + b1) @ W2, bf16 in/out, fp32 acc.
// R7: (1) W streams are fragment-ordered (W1F/W2F) -> every wf load is one
// coalesced global_load_dwordx4 (base + lane*16), prefetchable by the unroll;
// previously each was a 16-cache-line gather on the critical path (MfmaUtil
// 10%). (2) A-fragments hoisted to registers once (af[4][4]) and reused by
// both nh halves. LDS 66KB -> 2 blocks/CU; launch_bounds(256,2) gives the
// allocator the full 256-VGPR budget (no spills).
// ---------------------------------------------------------------------------
__global__ __launch_bounds__(256, 2) void gemm_fused_kernel(
    const unsigned short* __restrict__ A,     // [M][128] bf16
    const unsigned short* __restrict__ W1F,   // frag-ordered, 32768 shorts
    const float* __restrict__ b1,             // [256]
    const unsigned short* __restrict__ W2F,   // frag-ordered, 32768 shorts
    unsigned short* __restrict__ T,           // [M][128] bf16
    int M) {
    __shared__ unsigned short As[128 * 128];  // 32KB, chunk-swizzled
    __shared__ unsigned short Hs[128 * 136];  // 34KB, padded rows
    int tid = threadIdx.x;
    int wave = tid >> 6, lane = tid & 63;
    int m0 = blockIdx.x * 128;
    int wr = (wave & 1) * 64;
    int wcid = wave >> 1;
    int wc = wcid * 64;
    int fr = lane & 15, fq = lane >> 4;

    // stage A block: 2048 16B-chunks, 8 rounds of 256 lanes (XOR-swizzled)
    #pragma unroll
    for (int i = 0; i < 8; ++i) {
        int cbase = (i * 4 + wave) * 64;
        int c = cbase + lane;
        int m = c >> 4, cl = c & 15;
        int qg = ((cl & 7) ^ (m & 7)) | (cl & 8);
        int gm = m0 + m; if (gm >= M) gm = M - 1;
        const unsigned short* ga = A + (size_t)gm * 128 + qg * 8;
        __builtin_amdgcn_global_load_lds(
            (const __attribute__((address_space(1))) void*)ga,
            (__attribute__((address_space(3))) void*)(As + (size_t)cbase * 8),
            16, 0, 0);
    }
    __syncthreads();

    // A fragments to registers once; reused by both nh halves.
    bf16x8 af[4][4];   // [ks][mt]
    #pragma unroll
    for (int ks = 0; ks < 4; ++ks) {
        int q = ks * 4 + fq;
        int cl = ((q & 7) ^ (fr & 7)) | (q & 8);
        #pragma unroll
        for (int mt = 0; mt < 4; ++mt)
            af[ks][mt] = *(const bf16x8*)(As + (wr + mt * 16 + fr) * 128 + cl * 8);
    }

    const bf16x8* w1p = (const bf16x8*)W1F;
    const bf16x8* w2p = (const bf16x8*)W2F;

    f32x4 acc_t[4][4] = {};
    #pragma unroll
    for (int nh = 0; nh < 2; ++nh) {
        int wbase = (nh * 2 + wcid) * 16 * 64;   // 16 frags x 64 lanes per (nh,wc)
        // phase A: acc_h = A_tile @ W1[nh half]
        f32x4 acc_h[4][4] = {};
        #pragma unroll
        for (int ks = 0; ks < 4; ++ks) {
            bf16x8 wf[4];
            #pragma unroll
            for (int nt = 0; nt < 4; ++nt)
                wf[nt] = w1p[wbase + (ks * 4 + nt) * 64 + lane];
            #pragma unroll
            for (int mt = 0; mt < 4; ++mt)
                #pragma unroll
                for (int nt = 0; nt < 4; ++nt)
                    acc_h[mt][nt] = __builtin_amdgcn_mfma_f32_16x16x32_bf16(
                        af[ks][mt], wf[nt], acc_h[mt][nt], 0, 0, 0);
        }
        float bv[4];
        #pragma unroll
        for (int nt = 0; nt < 4; ++nt) bv[nt] = b1[nh * 128 + wc + nt * 16 + fr];
        __syncthreads();   // prior half's Hs consumers done
        #pragma unroll
        for (int mt = 0; mt < 4; ++mt)
            #pragma unroll
            for (int r = 0; r < 4; ++r) {
                int row = wr + mt * 16 + fq * 4 + r;
                #pragma unroll
                for (int nt = 0; nt < 4; ++nt) {
                    float v = fmaxf(acc_h[mt][nt][r] + bv[nt], 0.f);
                    Hs[row * 136 + wc + nt * 16 + fr] = f32_to_bf16(v);
                }
            }
        __syncthreads();   // Hs ready
        // phase B: acc_t += Hs @ W2[nh half rows]
        #pragma unroll
        for (int ks = 0; ks < 4; ++ks) {
            bf16x8 wf[4], hf[4];
            #pragma unroll
            for (int nt = 0; nt < 4; ++nt)
                wf[nt] = w2p[wbase + (ks * 4 + nt) * 64 + lane];
            #pragma unroll
            for (int mt = 0; mt < 4; ++mt)
                hf[mt] = *(const bf16x8*)(Hs + (wr + mt * 16 + fr) * 136 + ks * 32 + fq * 8);
            #pragma unroll
            for (int mt = 0; mt < 4; ++mt)
                #pragma unroll
                for (int nt = 0; nt < 4; ++nt)
                    acc_t[mt][nt] = __builtin_amdgcn_mfma_f32_16x16x32_bf16(
                        hf[mt], wf[nt], acc_t[mt][nt], 0, 0, 0);
        }
    }

    // epilogue: C/D layout col=lane&15, row=(lane>>4)*4+reg (m89-verified)
    #pragma unroll
    for (int mt = 0; mt < 4; ++mt)
        #pragma unroll
        for (int r = 0; r < 4; ++r) {
            int row = m0 + wr + mt * 16 + fq * 4 + r;
            if (row >= M) continue;
            #pragma unroll
            for (int nt = 0; nt < 4; ++nt)
                T[(size_t)row * 128 + wc + nt * 16 + fr] = f32_to_bf16(acc_t[mt][nt][r]);
        }
}

// ---------------------------------------------------------------------------
extern "C" void kernel_launch(void* const* d_in, const int* in_sizes, int n_in,
                              void* d_out, int out_size, void* d_ws, size_t ws_size,
                              hipStream_t stream) {
    const float* x  = (const float*)d_in[0];
    const int*   ei = (const int*)d_in[1];    // int32 (harness converts ints)
    const float* ew = (const float*)d_in[2];
    const float* W1 = (const float*)d_in[3];
    const float* b1 = (const float*)d_in[4];
    const float* W2 = (const float*)d_in[5];
    const float* b2 = (const float*)d_in[6];
    float* out = (float*)d_out;

    char* ws = (char*)d_ws;
    size_t off = 0;
    auto alloc = [&](size_t bytes) -> void* {
        void* p = ws + off;
        off = (off + bytes + 255) & ~(size_t)255;
        return p;
    };
    int*   cnt   = (int*)  alloc((size_t)N_NODES * 8);   // cnt + deg contiguous
    float* deg   = (float*)(cnt + N_NODES);
    float* dis   = (float*)alloc((size_t)N_NODES * 4);
    int*   rowp  = (int*)  alloc((size_t)(N_NODES + 1) * 4);
    int*   bsums = (int*)  alloc(512 * 4);
    int*   rank  = (int*)  alloc((size_t)N_EDGES * 4);
    int2*  pairs = (int2*) alloc((size_t)N_EDGES * 8);
    uint32_t* xb = (uint32_t*)alloc((size_t)N_NODES * IN_DIM * 2);
    unsigned short* W1F = (unsigned short*)alloc((size_t)IN_DIM * HID_DIM * 2);
    unsigned short* W2F = (unsigned short*)alloc((size_t)HID_DIM * OUT_DIM * 2);
    unsigned short* A1  = (unsigned short*)alloc((size_t)N_NODES * IN_DIM * 2);
    unsigned short* t   = (unsigned short*)alloc((size_t)N_NODES * OUT_DIM * 2);

    hipMemsetAsync(cnt, 0, (size_t)N_NODES * 8, stream);  // zeros cnt AND deg

    int ne_blocks = (N_EDGES + 255) / 256;
    int nn_blocks = (N_NODES + 255) / 256;   // 391

    rank_hist_kernel<<<ne_blocks, 256, 0, stream>>>(ei, ew, cnt, deg, rank);
    scan1_kernel<<<nn_blocks, 256, 0, stream>>>(cnt, rowp, bsums, N_NODES);
    scan2_kernel<<<1, 512, 0, stream>>>(bsums, nn_blocks);
    scan3_kernel<<<nn_blocks, 256, 0, stream>>>(rowp, bsums, deg, dis, N_NODES, N_EDGES);
    place_kernel<<<ne_blocks, 256, 0, stream>>>(ei, ew, rank, rowp, dis, pairs);
    prep_kernel<<<12756, 256, 0, stream>>>(x, xb, W1, W1F, W2, W2F);

    int agg_blocks = (N_NODES * 16) / 256;   // 6250, exact

    // layer 1 aggregate: A1 = agg(xb) [bf16]
    aggregate_kernel<true><<<agg_blocks, 256, 0, stream>>>(
        (const uint4*)xb, rowp, pairs, A1, nullptr);

    // fused dense stack: t = relu(A1 @ W1 + b1) @ W2  [bf16]
    gemm_fused_kernel<<<(N_NODES + 127) / 128, 256, 0, stream>>>(
        A1, W1F, b1, W2F, t, N_NODES);

    // layer 2 aggregate: out = agg(t) + b2 [fp32]
    aggregate_kernel<false><<<agg_blocks, 256, 0, stream>>>(
        (const uint4*)t, rowp, pairs, out, b2);
}

// Round 2
// 281.843 us; speedup vs baseline: 1.0993x; 1.0993x over previous
//
#include <hip/hip_runtime.h>
#include <hip/hip_bf16.h>
#include <cstdint>
#include <cstddef>

#define N_NODES 100000
#define N_EDGES 800000
#define IN_DIM 128
#define HID_DIM 256
#define OUT_DIM 128

typedef __attribute__((ext_vector_type(8))) short bf16x8;
typedef __attribute__((ext_vector_type(4))) float f32x4;

__device__ __forceinline__ unsigned short f32_to_bf16(float f) {
    __hip_bfloat16 b = __float2bfloat16(f);   // RNE
    return *reinterpret_cast<unsigned short*>(&b);
}
__device__ __forceinline__ float bf16_lo(uint32_t u) {
    uint32_t v = u << 16; return *reinterpret_cast<float*>(&v);
}
__device__ __forceinline__ float bf16_hi(uint32_t u) {
    uint32_t v = u & 0xffff0000u; return *reinterpret_cast<float*>(&v);
}

// ---------------------------------------------------------------------------
// R9: fused histogram + prep. The histogram's scattered device atomics are
// atomic-unit-throughput-bound (R1 counters: VALUBusy 0.3%, hbm 9%) — the
// machine is otherwise idle. Prep (bf16 convert + weight reorder) has no CSR
// dependency, so it runs in the same launch: hist blocks dispatch first and
// keep the atomic unit saturated; prep blocks backfill and soak bandwidth.
// deg is NOT atomically accumulated (R1 regression: 2nd atomic/edge doubled
// rank_hist 40->82 us); it is recomputed from the CSR sequentially.
// ---------------------------------------------------------------------------
#define HIST_BLOCKS 3125    // 3125*256 == 800000 exactly
#define XB_BLOCKS 12500     // 12500*256*4 == 100000*128

__global__ void hist_prep_kernel(const int* __restrict__ ei,
                                 int* __restrict__ cnt,
                                 int* __restrict__ rank,
                                 const float* __restrict__ x,
                                 uint32_t* __restrict__ xb,
                                 const float* __restrict__ W1,
                                 unsigned short* __restrict__ W1F,
                                 const float* __restrict__ W2,
                                 unsigned short* __restrict__ W2F) {
    int b = blockIdx.x;
    if (b < HIST_BLOCKS) {
        int e = b * 256 + threadIdx.x;
        rank[e] = atomicAdd(&cnt[ei[N_EDGES + e]], 1);
        return;
    }
    b -= HIST_BLOCKS;
    if (b < XB_BLOCKS) {                               // xb = bf16(x)
        int i = b * 256 + threadIdx.x;
        float4 v = ((const float4*)x)[i];
        uint32_t lo = (uint32_t)f32_to_bf16(v.x) | ((uint32_t)f32_to_bf16(v.y) << 16);
        uint32_t hi = (uint32_t)f32_to_bf16(v.z) | ((uint32_t)f32_to_bf16(v.w) << 16);
        ((uint2*)xb)[i] = make_uint2(lo, hi);
    } else if (b < XB_BLOCKS + 128) {                  // W1F: 32768 shorts
        int idx = (b - XB_BLOCKS) * 256 + threadIdx.x;
        int j = idx & 7, lane = (idx >> 3) & 63;
        int nt = (idx >> 9) & 3, ks = (idx >> 11) & 3;
        int wc = (idx >> 13) & 1, nh = (idx >> 14) & 1;
        int fr = lane & 15, fq = lane >> 4;
        int row = nh * 128 + wc * 64 + nt * 16 + fr;
        int kk = ks * 32 + fq * 8 + j;
        W1F[idx] = f32_to_bf16(W1[kk * HID_DIM + row]);
    } else {                                           // W2F: 32768 shorts
        int idx = (b - XB_BLOCKS - 128) * 256 + threadIdx.x;
        int j = idx & 7, lane = (idx >> 3) & 63;
        int nt = (idx >> 9) & 3, ks = (idx >> 11) & 3;
        int wc = (idx >> 13) & 1, nh = (idx >> 14) & 1;
        int fr = lane & 15, fq = lane >> 4;
        int n = wc * 64 + nt * 16 + fr;
        int kk = nh * 128 + ks * 32 + fq * 8 + j;
        W2F[idx] = f32_to_bf16(W2[kk * OUT_DIM + n]);
    }
}

__global__ void scan1_kernel(const int* __restrict__ in, int* __restrict__ out,
                             int* __restrict__ bsums, int n) {
    __shared__ int tmp[256];
    int t = threadIdx.x;
    int i = blockIdx.x * 256 + t;
    int v = (i < n) ? in[i] : 0;
    tmp[t] = v;
    __syncthreads();
    for (int off = 1; off < 256; off <<= 1) {
        int u = (t >= off) ? tmp[t - off] : 0;
        __syncthreads();
        tmp[t] += u;
        __syncthreads();
    }
    if (i < n) out[i] = tmp[t] - v;          // exclusive
    if (t == 255) bsums[blockIdx.x] = tmp[255];
}

__global__ void scan2_kernel(int* __restrict__ bsums, int nb) {
    __shared__ int tmp[512];
    int t = threadIdx.x;
    int v = (t < nb) ? bsums[t] : 0;
    tmp[t] = v;
    __syncthreads();
    for (int off = 1; off < 512; off <<= 1) {
        int u = (t >= off) ? tmp[t - off] : 0;
        __syncthreads();
        tmp[t] += u;
        __syncthreads();
    }
    if (t < nb) bsums[t] = tmp[t] - v;       // exclusive
}

__global__ void scan3_kernel(int* __restrict__ rowp, const int* __restrict__ bsums,
                             int n, int total) {
    int i = blockIdx.x * 256 + threadIdx.x;
    if (i == 0) rowp[n] = total;
    if (i >= n) return;
    rowp[i] += bsums[blockIdx.x];
}

// place: no atomics — slot = rowp[col] + rank[e]. Stores RAW weight; the
// normalization is applied by normalize_kernel once dis is known.
__global__ void place_kernel(const int* __restrict__ ei,
                             const float* __restrict__ ew,
                             const int* __restrict__ rank,
                             const int* __restrict__ rowp,
                             int2* __restrict__ pairs) {
    int e = blockIdx.x * 256 + threadIdx.x;
    if (e >= N_EDGES) return;
    int c = ei[N_EDGES + e];
    int pos = rowp[c] + rank[e];
    pairs[pos] = make_int2(ei[e], __float_as_int(ew[e]));
}

// per-node: deg = sum of raw row weights; dis = rsqrt(deg) or 0. No atomics.
__global__ void deg_dis_kernel(const int* __restrict__ rowp,
                               const int2* __restrict__ pairs,
                               float* __restrict__ dis) {
    int v = blockIdx.x * 256 + threadIdx.x;
    if (v >= N_NODES) return;
    int b = rowp[v], e = rowp[v + 1];
    float d = 0.f;
    for (int j = b; j < e; ++j) d += __int_as_float(pairs[j].y);
    dis[v] = d > 0.f ? rsqrtf(d) : 0.f;
}

// pairs[j].y <- w * dis[src] * dis[dst]. dis is 400KB (L2-resident) so the
// src gathers are cheap here; both aggregates then skip dis entirely.
__global__ void normalize_kernel(const int* __restrict__ rowp,
                                 int2* __restrict__ pairs,
                                 const float* __restrict__ dis) {
    int v = blockIdx.x * 256 + threadIdx.x;
    if (v >= N_NODES) return;
    float dv = dis[v];
    int b = rowp[v], e = rowp[v + 1];
    for (int j = b; j < e; ++j) {
        int2 p = pairs[j];
        p.y = __float_as_int(__int_as_float(p.y) * dis[p.x] * dv);
        pairs[j] = p;
    }
}

// ---------------------------------------------------------------------------
// Aggregation: 4 nodes per wave (16 lanes/node, uint4 = 8 bf16 dims/lane).
// Weight in pairs[].y is pre-normalized so the inner loop is gather+fma only.
// ---------------------------------------------------------------------------
__device__ __forceinline__ void acc_edge(float w, uint4 u, float* a) {
    a[0] += w * bf16_lo(u.x); a[1] += w * bf16_hi(u.x);
    a[2] += w * bf16_lo(u.y); a[3] += w * bf16_hi(u.y);
    a[4] += w * bf16_lo(u.z); a[5] += w * bf16_hi(u.z);
    a[6] += w * bf16_lo(u.w); a[7] += w * bf16_hi(u.w);
}

template <bool OUT_BF16>
__global__ void aggregate_kernel(const uint4* __restrict__ feat,
                                 const int* __restrict__ rowp,
                                 const int2* __restrict__ pairs,
                                 void* __restrict__ out_v,
                                 const float* __restrict__ bias) {
    int gtid = blockIdx.x * blockDim.x + threadIdx.x;
    int node = gtid >> 4;
    int lane = threadIdx.x & 15;
    if (node >= N_NODES) return;
    int beg = rowp[node], end = rowp[node + 1];
    float a[8] = {};

    int j = beg;
    for (; j + 4 <= end; j += 4) {
        int2 p[4]; uint4 u[4];
        #pragma unroll
        for (int q = 0; q < 4; ++q) p[q] = pairs[j + q];
        #pragma unroll
        for (int q = 0; q < 4; ++q) u[q] = feat[(size_t)p[q].x * 16 + lane];
        #pragma unroll
        for (int q = 0; q < 4; ++q) acc_edge(__int_as_float(p[q].y), u[q], a);
    }
    if (j + 2 <= end) {
        int2 p0 = pairs[j], p1 = pairs[j + 1];
        uint4 u0 = feat[(size_t)p0.x * 16 + lane];
        uint4 u1 = feat[(size_t)p1.x * 16 + lane];
        acc_edge(__int_as_float(p0.y), u0, a);
        acc_edge(__int_as_float(p1.y), u1, a);
        j += 2;
    }
    if (j < end) {
        int2 p0 = pairs[j];
        uint4 u0 = feat[(size_t)p0.x * 16 + lane];
        acc_edge(__int_as_float(p0.y), u0, a);
    }
    if (bias) {
        float4 b0 = ((const float4*)bias)[lane * 2];
        float4 b1 = ((const float4*)bias)[lane * 2 + 1];
        a[0] += b0.x; a[1] += b0.y; a[2] += b0.z; a[3] += b0.w;
        a[4] += b1.x; a[5] += b1.y; a[6] += b1.z; a[7] += b1.w;
    }
    if (OUT_BF16) {
        uint4 o;
        o.x = (uint32_t)f32_to_bf16(a[0]) | ((uint32_t)f32_to_bf16(a[1]) << 16);
        o.y = (uint32_t)f32_to_bf16(a[2]) | ((uint32_t)f32_to_bf16(a[3]) << 16);
        o.z = (uint32_t)f32_to_bf16(a[4]) | ((uint32_t)f32_to_bf16(a[5]) << 16);
        o.w = (uint32_t)f32_to_bf16(a[6]) | ((uint32_t)f32_to_bf16(a[7]) << 16);
        ((uint4*)out_v)[(size_t)node * 16 + lane] = o;
    } else {
        ((float4*)out_v)[(size_t)node * 32 + lane * 2] =
            make_float4(a[0], a[1], a[2], a[3]);
        ((float4*)out_v)[(size_t)node * 32 + lane * 2 + 1] =
            make_float4(a[4], a[5], a[6], a[7]);
    }
}

// ---------------------------------------------------------------------------
// Fused 2-layer GEMM: T = relu(A @ W1 + b1) @ W2, bf16 in/out, fp32 acc.
// W streams are fragment-ordered (W1F/W2F) -> every wf load is one coalesced
// global_load_dwordx4; A-fragments hoisted to registers once (af[4][4]).
// LDS 66KB -> 2 blocks/CU; launch_bounds(256,2).
// ---------------------------------------------------------------------------
__global__ __launch_bounds__(256, 2) void gemm_fused_kernel(
    const unsigned short* __restrict__ A,     // [M][128] bf16
    const unsigned short* __restrict__ W1F,   // frag-ordered, 32768 shorts
    const float* __restrict__ b1,             // [256]
    const unsigned short* __restrict__ W2F,   // frag-ordered, 32768 shorts
    unsigned short* __restrict__ T,           // [M][128] bf16
    int M) {
    __shared__ unsigned short As[128 * 128];  // 32KB, chunk-swizzled
    __shared__ unsigned short Hs[128 * 136];  // 34KB, padded rows
    int tid = threadIdx.x;
    int wave = tid >> 6, lane = tid & 63;
    int m0 = blockIdx.x * 128;
    int wr = (wave & 1) * 64;
    int wcid = wave >> 1;
    int wc = wcid * 64;
    int fr = lane & 15, fq = lane >> 4;

    // stage A block: 2048 16B-chunks, 8 rounds of 256 lanes (XOR-swizzled)
    #pragma unroll
    for (int i = 0; i < 8; ++i) {
        int cbase = (i * 4 + wave) * 64;
        int c = cbase + lane;
        int m = c >> 4, cl = c & 15;
        int qg = ((cl & 7) ^ (m & 7)) | (cl & 8);
        int gm = m0 + m; if (gm >= M) gm = M - 1;
        const unsigned short* ga = A + (size_t)gm * 128 + qg * 8;
        __builtin_amdgcn_global_load_lds(
            (const __attribute__((address_space(1))) void*)ga,
            (__attribute__((address_space(3))) void*)(As + (size_t)cbase * 8),
            16, 0, 0);
    }
    __syncthreads();

    // A fragments to registers once; reused by both nh halves.
    bf16x8 af[4][4];   // [ks][mt]
    #pragma unroll
    for (int ks = 0; ks < 4; ++ks) {
        int q = ks * 4 + fq;
        int cl = ((q & 7) ^ (fr & 7)) | (q & 8);
        #pragma unroll
        for (int mt = 0; mt < 4; ++mt)
            af[ks][mt] = *(const bf16x8*)(As + (wr + mt * 16 + fr) * 128 + cl * 8);
    }

    const bf16x8* w1p = (const bf16x8*)W1F;
    const bf16x8* w2p = (const bf16x8*)W2F;

    f32x4 acc_t[4][4] = {};
    #pragma unroll
    for (int nh = 0; nh < 2; ++nh) {
        int wbase = (nh * 2 + wcid) * 16 * 64;   // 16 frags x 64 lanes per (nh,wc)
        // phase A: acc_h = A_tile @ W1[nh half]
        f32x4 acc_h[4][4] = {};
        #pragma unroll
        for (int ks = 0; ks < 4; ++ks) {
            bf16x8 wf[4];
            #pragma unroll
            for (int nt = 0; nt < 4; ++nt)
                wf[nt] = w1p[wbase + (ks * 4 + nt) * 64 + lane];
            #pragma unroll
            for (int mt = 0; mt < 4; ++mt)
                #pragma unroll
                for (int nt = 0; nt < 4; ++nt)
                    acc_h[mt][nt] = __builtin_amdgcn_mfma_f32_16x16x32_bf16(
                        af[ks][mt], wf[nt], acc_h[mt][nt], 0, 0, 0);
        }
        float bv[4];
        #pragma unroll
        for (int nt = 0; nt < 4; ++nt) bv[nt] = b1[nh * 128 + wc + nt * 16 + fr];
        __syncthreads();   // prior half's Hs consumers done
        #pragma unroll
        for (int mt = 0; mt < 4; ++mt)
            #pragma unroll
            for (int r = 0; r < 4; ++r) {
                int row = wr + mt * 16 + fq * 4 + r;
                #pragma unroll
                for (int nt = 0; nt < 4; ++nt) {
                    float v = fmaxf(acc_h[mt][nt][r] + bv[nt], 0.f);
                    Hs[row * 136 + wc + nt * 16 + fr] = f32_to_bf16(v);
                }
            }
        __syncthreads();   // Hs ready
        // phase B: acc_t += Hs @ W2[nh half rows]
        #pragma unroll
        for (int ks = 0; ks < 4; ++ks) {
            bf16x8 wf[4], hf[4];
            #pragma unroll
            for (int nt = 0; nt < 4; ++nt)
                wf[nt] = w2p[wbase + (ks * 4 + nt) * 64 + lane];
            #pragma unroll
            for (int mt = 0; mt < 4; ++mt)
                hf[mt] = *(const bf16x8*)(Hs + (wr + mt * 16 + fr) * 136 + ks * 32 + fq * 8);
            #pragma unroll
            for (int mt = 0; mt < 4; ++mt)
                #pragma unroll
                for (int nt = 0; nt < 4; ++nt)
                    acc_t[mt][nt] = __builtin_amdgcn_mfma_f32_16x16x32_bf16(
                        hf[mt], wf[nt], acc_t[mt][nt], 0, 0, 0);
        }
    }

    // epilogue: C/D layout col=lane&15, row=(lane>>4)*4+reg (m89-verified)
    #pragma unroll
    for (int mt = 0; mt < 4; ++mt)
        #pragma unroll
        for (int r = 0; r < 4; ++r) {
            int row = m0 + wr + mt * 16 + fq * 4 + r;
            if (row >= M) continue;
            #pragma unroll
            for (int nt = 0; nt < 4; ++nt)
                T[(size_t)row * 128 + wc + nt * 16 + fr] = f32_to_bf16(acc_t[mt][nt][r]);
        }
}

// ---------------------------------------------------------------------------
extern "C" void kernel_launch(void* const* d_in, const int* in_sizes, int n_in,
                              void* d_out, int out_size, void* d_ws, size_t ws_size,
                              hipStream_t stream) {
    const float* x  = (const float*)d_in[0];
    const int*   ei = (const int*)d_in[1];    // int32 (harness converts ints)
    const float* ew = (const float*)d_in[2];
    const float* W1 = (const float*)d_in[3];
    const float* b1 = (const float*)d_in[4];
    const float* W2 = (const float*)d_in[5];
    const float* b2 = (const float*)d_in[6];
    float* out = (float*)d_out;

    char* ws = (char*)d_ws;
    size_t off = 0;
    auto alloc = [&](size_t bytes) -> void* {
        void* p = ws + off;
        off = (off + bytes + 255) & ~(size_t)255;
        return p;
    };
    int*   cnt   = (int*)  alloc((size_t)N_NODES * 4);
    float* dis   = (float*)alloc((size_t)N_NODES * 4);
    int*   rowp  = (int*)  alloc((size_t)(N_NODES + 1) * 4);
    int*   bsums = (int*)  alloc(512 * 4);
    int*   rank  = (int*)  alloc((size_t)N_EDGES * 4);
    int2*  pairs = (int2*) alloc((size_t)N_EDGES * 8);
    uint32_t* xb = (uint32_t*)alloc((size_t)N_NODES * IN_DIM * 2);
    unsigned short* W1F = (unsigned short*)alloc((size_t)IN_DIM * HID_DIM * 2);
    unsigned short* W2F = (unsigned short*)alloc((size_t)HID_DIM * OUT_DIM * 2);
    unsigned short* A1  = (unsigned short*)alloc((size_t)N_NODES * IN_DIM * 2);
    unsigned short* t   = (unsigned short*)alloc((size_t)N_NODES * OUT_DIM * 2);

    hipMemsetAsync(cnt, 0, (size_t)N_NODES * 4, stream);

    int nn_blocks = (N_NODES + 255) / 256;   // 391
    int ne_blocks = (N_EDGES + 255) / 256;   // 3125

    // fused: histogram (atomic-unit-bound) overlapped with prep (BW-bound)
    hist_prep_kernel<<<HIST_BLOCKS + XB_BLOCKS + 256, 256, 0, stream>>>(
        ei, cnt, rank, x, xb, W1, W1F, W2, W2F);

    scan1_kernel<<<nn_blocks, 256, 0, stream>>>(cnt, rowp, bsums, N_NODES);
    scan2_kernel<<<1, 512, 0, stream>>>(bsums, nn_blocks);
    scan3_kernel<<<nn_blocks, 256, 0, stream>>>(rowp, bsums, N_NODES, N_EDGES);
    place_kernel<<<ne_blocks, 256, 0, stream>>>(ei, ew, rank, rowp, pairs);
    deg_dis_kernel<<<nn_blocks, 256, 0, stream>>>(rowp, pairs, dis);
    normalize_kernel<<<nn_blocks, 256, 0, stream>>>(rowp, pairs, dis);

    int agg_blocks = (N_NODES * 16) / 256;   // 6250, exact

    // layer 1 aggregate: A1 = agg(xb) [bf16]
    aggregate_kernel<true><<<agg_blocks, 256, 0, stream>>>(
        (const uint4*)xb, rowp, pairs, A1, nullptr);

    // fused dense stack: t = relu(A1 @ W1 + b1) @ W2  [bf16]
    gemm_fused_kernel<<<(N_NODES + 127) / 128, 256, 0, stream>>>(
        A1, W1F, b1, W2F, t, N_NODES);

    // layer 2 aggregate: out = agg(t) + b2 [fp32]
    aggregate_kernel<false><<<agg_blocks, 256, 0, stream>>>(
        (const uint4*)t, rowp, pairs, out, b2);
}

// Round 3
// 277.156 us; speedup vs baseline: 1.1179x; 1.0169x over previous
//
#include <hip/hip_runtime.h>
#include <hip/hip_bf16.h>
#include <cstdint>
#include <cstddef>

#define N_NODES 100000
#define N_EDGES 800000
#define IN_DIM 128
#define HID_DIM 256
#define OUT_DIM 128

// deg fixed-point scale: 2^21. Max per-node wsum before low-word carry is
// 2^11 edges/node; random graph max-degree ~30. Per-edge quant error 2^-21.
#define DEG_SCALE 2097152.0f
#define DEG_INV   (1.0f / 2097152.0f)

typedef __attribute__((ext_vector_type(8))) short bf16x8;
typedef __attribute__((ext_vector_type(4))) float f32x4;

__device__ __forceinline__ unsigned short f32_to_bf16(float f) {
    __hip_bfloat16 b = __float2bfloat16(f);   // RNE
    return *reinterpret_cast<unsigned short*>(&b);
}
__device__ __forceinline__ float bf16_lo(uint32_t u) {
    uint32_t v = u << 16; return *reinterpret_cast<float*>(&v);
}
__device__ __forceinline__ float bf16_hi(uint32_t u) {
    uint32_t v = u & 0xffff0000u; return *reinterpret_cast<float*>(&v);
}

// ---------------------------------------------------------------------------
// Fused histogram + prep. Histogram is atomic-unit-bound (R1/R2 counters:
// VALUBusy ~2%, hbm ~22%) so prep blocks backfill and soak bandwidth.
// R10: ONE u64 atomic per edge carries BOTH count (high word) and fixed-point
// weight sum (low word). R1 showed a 2nd atomic instruction doubles the
// histogram; a wider single RMW should not. This makes deg/dis available at
// scan time -> deg_dis and normalize passes are deleted.
// ---------------------------------------------------------------------------
#define HIST_BLOCKS 3125    // 3125*256 == 800000 exactly
#define XB_BLOCKS 12500     // 12500*256*4 == 100000*128

__global__ void hist_prep_kernel(const int* __restrict__ ei,
                                 const float* __restrict__ ew,
                                 unsigned long long* __restrict__ cnt64,
                                 int* __restrict__ rank,
                                 const float* __restrict__ x,
                                 uint32_t* __restrict__ xb,
                                 const float* __restrict__ W1,
                                 unsigned short* __restrict__ W1F,
                                 const float* __restrict__ W2,
                                 unsigned short* __restrict__ W2F) {
    int b = blockIdx.x;
    if (b < HIST_BLOCKS) {
        int e = b * 256 + threadIdx.x;
        int c = ei[N_EDGES + e];
        uint32_t wfix = (uint32_t)(ew[e] * DEG_SCALE + 0.5f);
        unsigned long long add = (1ULL << 32) | (unsigned long long)wfix;
        unsigned long long old = atomicAdd(&cnt64[c], add);
        rank[e] = (int)(old >> 32);
        return;
    }
    b -= HIST_BLOCKS;
    if (b < XB_BLOCKS) {                               // xb = bf16(x)
        int i = b * 256 + threadIdx.x;
        float4 v = ((const float4*)x)[i];
        uint32_t lo = (uint32_t)f32_to_bf16(v.x) | ((uint32_t)f32_to_bf16(v.y) << 16);
        uint32_t hi = (uint32_t)f32_to_bf16(v.z) | ((uint32_t)f32_to_bf16(v.w) << 16);
        ((uint2*)xb)[i] = make_uint2(lo, hi);
    } else if (b < XB_BLOCKS + 128) {                  // W1F: 32768 shorts
        int idx = (b - XB_BLOCKS) * 256 + threadIdx.x;
        int j = idx & 7, lane = (idx >> 3) & 63;
        int nt = (idx >> 9) & 3, ks = (idx >> 11) & 3;
        int wc = (idx >> 13) & 1, nh = (idx >> 14) & 1;
        int fr = lane & 15, fq = lane >> 4;
        int row = nh * 128 + wc * 64 + nt * 16 + fr;
        int kk = ks * 32 + fq * 8 + j;
        W1F[idx] = f32_to_bf16(W1[kk * HID_DIM + row]);
    } else {                                           // W2F: 32768 shorts
        int idx = (b - XB_BLOCKS - 128) * 256 + threadIdx.x;
        int j = idx & 7, lane = (idx >> 3) & 63;
        int nt = (idx >> 9) & 3, ks = (idx >> 11) & 3;
        int wc = (idx >> 13) & 1, nh = (idx >> 14) & 1;
        int fr = lane & 15, fq = lane >> 4;
        int n = wc * 64 + nt * 16 + fr;
        int kk = nh * 128 + ks * 32 + fq * 8 + j;
        W2F[idx] = f32_to_bf16(W2[kk * OUT_DIM + n]);
    }
}

// scan1: block-exclusive scan of counts (high words); also emits dis from
// the packed weight sums (low words) — deg_dis pass eliminated.
__global__ void scan1_kernel(const unsigned long long* __restrict__ cnt64,
                             int* __restrict__ out, int* __restrict__ bsums,
                             float* __restrict__ dis, int n) {
    __shared__ int tmp[256];
    int t = threadIdx.x;
    int i = blockIdx.x * 256 + t;
    unsigned long long cv = (i < n) ? cnt64[i] : 0ULL;
    int v = (int)(cv >> 32);
    tmp[t] = v;
    __syncthreads();
    for (int off = 1; off < 256; off <<= 1) {
        int u = (t >= off) ? tmp[t - off] : 0;
        __syncthreads();
        tmp[t] += u;
        __syncthreads();
    }
    if (i < n) {
        out[i] = tmp[t] - v;                 // exclusive
        uint32_t wf = (uint32_t)cv;
        dis[i] = wf ? rsqrtf((float)wf * DEG_INV) : 0.f;
    }
    if (t == 255) bsums[blockIdx.x] = tmp[255];
}

// scan2+scan3 fused: each block reduces its own bsums prefix (<=391 ints).
__global__ void scan23_kernel(int* __restrict__ rowp, const int* __restrict__ bsums,
                              int n, int total) {
    __shared__ int red[256];
    int b = blockIdx.x, t = threadIdx.x;
    int s = 0;
    for (int i = t; i < b; i += 256) s += bsums[i];
    red[t] = s;
    __syncthreads();
    for (int off = 128; off > 0; off >>= 1) {
        if (t < off) red[t] += red[t + off];
        __syncthreads();
    }
    int pre = red[0];
    int i = b * 256 + t;
    if (i == 0) rowp[n] = total;
    if (i < n) rowp[i] += pre;
}

// place: no atomics — slot = rowp[col] + rank[e]. Writes the FULLY
// NORMALIZED weight (dis ready since scan1); both aggregates skip dis.
__global__ void place_kernel(const int* __restrict__ ei,
                             const float* __restrict__ ew,
                             const int* __restrict__ rank,
                             const int* __restrict__ rowp,
                             const float* __restrict__ dis,
                             int2* __restrict__ pairs) {
    int e = blockIdx.x * 256 + threadIdx.x;
    if (e >= N_EDGES) return;
    int s = ei[e];
    int c = ei[N_EDGES + e];
    int pos = rowp[c] + rank[e];
    float wn = ew[e] * dis[s] * dis[c];      // dis: 400KB, L2-resident
    pairs[pos] = make_int2(s, __float_as_int(wn));
}

// ---------------------------------------------------------------------------
// Aggregation: 4 nodes per wave (16 lanes/node, uint4 = 8 bf16 dims/lane).
// Weight pre-normalized -> inner loop is gather+fma only. R10: unroll 8
// (128B in flight per lane) to probe latency vs gather-throughput bound.
// ---------------------------------------------------------------------------
__device__ __forceinline__ void acc_edge(float w, uint4 u, float* a) {
    a[0] += w * bf16_lo(u.x); a[1] += w * bf16_hi(u.x);
    a[2] += w * bf16_lo(u.y); a[3] += w * bf16_hi(u.y);
    a[4] += w * bf16_lo(u.z); a[5] += w * bf16_hi(u.z);
    a[6] += w * bf16_lo(u.w); a[7] += w * bf16_hi(u.w);
}

template <bool OUT_BF16>
__global__ void aggregate_kernel(const uint4* __restrict__ feat,
                                 const int* __restrict__ rowp,
                                 const int2* __restrict__ pairs,
                                 void* __restrict__ out_v,
                                 const float* __restrict__ bias) {
    int gtid = blockIdx.x * blockDim.x + threadIdx.x;
    int node = gtid >> 4;
    int lane = threadIdx.x & 15;
    if (node >= N_NODES) return;
    int beg = rowp[node], end = rowp[node + 1];
    float a[8] = {};

    int j = beg;
    for (; j + 8 <= end; j += 8) {
        int2 p[8]; uint4 u[8];
        #pragma unroll
        for (int q = 0; q < 8; ++q) p[q] = pairs[j + q];
        #pragma unroll
        for (int q = 0; q < 8; ++q) u[q] = feat[(size_t)p[q].x * 16 + lane];
        #pragma unroll
        for (int q = 0; q < 8; ++q) acc_edge(__int_as_float(p[q].y), u[q], a);
    }
    if (j + 4 <= end) {
        int2 p[4]; uint4 u[4];
        #pragma unroll
        for (int q = 0; q < 4; ++q) p[q] = pairs[j + q];
        #pragma unroll
        for (int q = 0; q < 4; ++q) u[q] = feat[(size_t)p[q].x * 16 + lane];
        #pragma unroll
        for (int q = 0; q < 4; ++q) acc_edge(__int_as_float(p[q].y), u[q], a);
        j += 4;
    }
    if (j + 2 <= end) {
        int2 p0 = pairs[j], p1 = pairs[j + 1];
        uint4 u0 = feat[(size_t)p0.x * 16 + lane];
        uint4 u1 = feat[(size_t)p1.x * 16 + lane];
        acc_edge(__int_as_float(p0.y), u0, a);
        acc_edge(__int_as_float(p1.y), u1, a);
        j += 2;
    }
    if (j < end) {
        int2 p0 = pairs[j];
        uint4 u0 = feat[(size_t)p0.x * 16 + lane];
        acc_edge(__int_as_float(p0.y), u0, a);
    }
    if (bias) {
        float4 b0 = ((const float4*)bias)[lane * 2];
        float4 b1 = ((const float4*)bias)[lane * 2 + 1];
        a[0] += b0.x; a[1] += b0.y; a[2] += b0.z; a[3] += b0.w;
        a[4] += b1.x; a[5] += b1.y; a[6] += b1.z; a[7] += b1.w;
    }
    if (OUT_BF16) {
        uint4 o;
        o.x = (uint32_t)f32_to_bf16(a[0]) | ((uint32_t)f32_to_bf16(a[1]) << 16);
        o.y = (uint32_t)f32_to_bf16(a[2]) | ((uint32_t)f32_to_bf16(a[3]) << 16);
        o.z = (uint32_t)f32_to_bf16(a[4]) | ((uint32_t)f32_to_bf16(a[5]) << 16);
        o.w = (uint32_t)f32_to_bf16(a[6]) | ((uint32_t)f32_to_bf16(a[7]) << 16);
        ((uint4*)out_v)[(size_t)node * 16 + lane] = o;
    } else {
        ((float4*)out_v)[(size_t)node * 32 + lane * 2] =
            make_float4(a[0], a[1], a[2], a[3]);
        ((float4*)out_v)[(size_t)node * 32 + lane * 2 + 1] =
            make_float4(a[4], a[5], a[6], a[7]);
    }
}

// ---------------------------------------------------------------------------
// Fused 2-layer GEMM: T = relu(A @ W1 + b1) @ W2, bf16 in/out, fp32 acc.
// W streams are fragment-ordered (W1F/W2F) -> every wf load is one coalesced
// global_load_dwordx4; A-fragments hoisted to registers once (af[4][4]).
// LDS 66KB -> 2 blocks/CU; launch_bounds(256,2).
// ---------------------------------------------------------------------------
__global__ __launch_bounds__(256, 2) void gemm_fused_kernel(
    const unsigned short* __restrict__ A,     // [M][128] bf16
    const unsigned short* __restrict__ W1F,   // frag-ordered, 32768 shorts
    const float* __restrict__ b1,             // [256]
    const unsigned short* __restrict__ W2F,   // frag-ordered, 32768 shorts
    unsigned short* __restrict__ T,           // [M][128] bf16
    int M) {
    __shared__ unsigned short As[128 * 128];  // 32KB, chunk-swizzled
    __shared__ unsigned short Hs[128 * 136];  // 34KB, padded rows
    int tid = threadIdx.x;
    int wave = tid >> 6, lane = tid & 63;
    int m0 = blockIdx.x * 128;
    int wr = (wave & 1) * 64;
    int wcid = wave >> 1;
    int wc = wcid * 64;
    int fr = lane & 15, fq = lane >> 4;

    // stage A block: 2048 16B-chunks, 8 rounds of 256 lanes (XOR-swizzled)
    #pragma unroll
    for (int i = 0; i < 8; ++i) {
        int cbase = (i * 4 + wave) * 64;
        int c = cbase + lane;
        int m = c >> 4, cl = c & 15;
        int qg = ((cl & 7) ^ (m & 7)) | (cl & 8);
        int gm = m0 + m; if (gm >= M) gm = M - 1;
        const unsigned short* ga = A + (size_t)gm * 128 + qg * 8;
        __builtin_amdgcn_global_load_lds(
            (const __attribute__((address_space(1))) void*)ga,
            (__attribute__((address_space(3))) void*)(As + (size_t)cbase * 8),
            16, 0, 0);
    }
    __syncthreads();

    // A fragments to registers once; reused by both nh halves.
    bf16x8 af[4][4];   // [ks][mt]
    #pragma unroll
    for (int ks = 0; ks < 4; ++ks) {
        int q = ks * 4 + fq;
        int cl = ((q & 7) ^ (fr & 7)) | (q & 8);
        #pragma unroll
        for (int mt = 0; mt < 4; ++mt)
            af[ks][mt] = *(const bf16x8*)(As + (wr + mt * 16 + fr) * 128 + cl * 8);
    }

    const bf16x8* w1p = (const bf16x8*)W1F;
    const bf16x8* w2p = (const bf16x8*)W2F;

    f32x4 acc_t[4][4] = {};
    #pragma unroll
    for (int nh = 0; nh < 2; ++nh) {
        int wbase = (nh * 2 + wcid) * 16 * 64;   // 16 frags x 64 lanes per (nh,wc)
        // phase A: acc_h = A_tile @ W1[nh half]
        f32x4 acc_h[4][4] = {};
        #pragma unroll
        for (int ks = 0; ks < 4; ++ks) {
            bf16x8 wf[4];
            #pragma unroll
            for (int nt = 0; nt < 4; ++nt)
                wf[nt] = w1p[wbase + (ks * 4 + nt) * 64 + lane];
            #pragma unroll
            for (int mt = 0; mt < 4; ++mt)
                #pragma unroll
                for (int nt = 0; nt < 4; ++nt)
                    acc_h[mt][nt] = __builtin_amdgcn_mfma_f32_16x16x32_bf16(
                        af[ks][mt], wf[nt], acc_h[mt][nt], 0, 0, 0);
        }
        float bv[4];
        #pragma unroll
        for (int nt = 0; nt < 4; ++nt) bv[nt] = b1[nh * 128 + wc + nt * 16 + fr];
        __syncthreads();   // prior half's Hs consumers done
        #pragma unroll
        for (int mt = 0; mt < 4; ++mt)
            #pragma unroll
            for (int r = 0; r < 4; ++r) {
                int row = wr + mt * 16 + fq * 4 + r;
                #pragma unroll
                for (int nt = 0; nt < 4; ++nt) {
                    float v = fmaxf(acc_h[mt][nt][r] + bv[nt], 0.f);
                    Hs[row * 136 + wc + nt * 16 + fr] = f32_to_bf16(v);
                }
            }
        __syncthreads();   // Hs ready
        // phase B: acc_t += Hs @ W2[nh half rows]
        #pragma unroll
        for (int ks = 0; ks < 4; ++ks) {
            bf16x8 wf[4], hf[4];
            #pragma unroll
            for (int nt = 0; nt < 4; ++nt)
                wf[nt] = w2p[wbase + (ks * 4 + nt) * 64 + lane];
            #pragma unroll
            for (int mt = 0; mt < 4; ++mt)
                hf[mt] = *(const bf16x8*)(Hs + (wr + mt * 16 + fr) * 136 + ks * 32 + fq * 8);
            #pragma unroll
            for (int mt = 0; mt < 4; ++mt)
                #pragma unroll
                for (int nt = 0; nt < 4; ++nt)
                    acc_t[mt][nt] = __builtin_amdgcn_mfma_f32_16x16x32_bf16(
                        hf[mt], wf[nt], acc_t[mt][nt], 0, 0, 0);
        }
    }

    // epilogue: C/D layout col=lane&15, row=(lane>>4)*4+reg (m89-verified)
    #pragma unroll
    for (int mt = 0; mt < 4; ++mt)
        #pragma unroll
        for (int r = 0; r < 4; ++r) {
            int row = m0 + wr + mt * 16 + fq * 4 + r;
            if (row >= M) continue;
            #pragma unroll
            for (int nt = 0; nt < 4; ++nt)
                T[(size_t)row * 128 + wc + nt * 16 + fr] = f32_to_bf16(acc_t[mt][nt][r]);
        }
}

// ---------------------------------------------------------------------------
extern "C" void kernel_launch(void* const* d_in, const int* in_sizes, int n_in,
                              void* d_out, int out_size, void* d_ws, size_t ws_size,
                              hipStream_t stream) {
    const float* x  = (const float*)d_in[0];
    const int*   ei = (const int*)d_in[1];    // int32 (harness converts ints)
    const float* ew = (const float*)d_in[2];
    const float* W1 = (const float*)d_in[3];
    const float* b1 = (const float*)d_in[4];
    const float* W2 = (const float*)d_in[5];
    const float* b2 = (const float*)d_in[6];
    float* out = (float*)d_out;

    char* ws = (char*)d_ws;
    size_t off = 0;
    auto alloc = [&](size_t bytes) -> void* {
        void* p = ws + off;
        off = (off + bytes + 255) & ~(size_t)255;
        return p;
    };
    unsigned long long* cnt64 = (unsigned long long*)alloc((size_t)N_NODES * 8);
    float* dis   = (float*)alloc((size_t)N_NODES * 4);
    int*   rowp  = (int*)  alloc((size_t)(N_NODES + 1) * 4);
    int*   bsums = (int*)  alloc(512 * 4);
    int*   rank  = (int*)  alloc((size_t)N_EDGES * 4);
    int2*  pairs = (int2*) alloc((size_t)N_EDGES * 8);
    uint32_t* xb = (uint32_t*)alloc((size_t)N_NODES * IN_DIM * 2);
    unsigned short* W1F = (unsigned short*)alloc((size_t)IN_DIM * HID_DIM * 2);
    unsigned short* W2F = (unsigned short*)alloc((size_t)HID_DIM * OUT_DIM * 2);
    unsigned short* A1  = (unsigned short*)alloc((size_t)N_NODES * IN_DIM * 2);
    unsigned short* t   = (unsigned short*)alloc((size_t)N_NODES * OUT_DIM * 2);

    hipMemsetAsync(cnt64, 0, (size_t)N_NODES * 8, stream);

    int nn_blocks = (N_NODES + 255) / 256;   // 391
    int ne_blocks = (N_EDGES + 255) / 256;   // 3125

    // fused: histogram (atomic-unit-bound) overlapped with prep (BW-bound)
    hist_prep_kernel<<<HIST_BLOCKS + XB_BLOCKS + 256, 256, 0, stream>>>(
        ei, ew, cnt64, rank, x, xb, W1, W1F, W2, W2F);

    scan1_kernel<<<nn_blocks, 256, 0, stream>>>(cnt64, rowp, bsums, dis, N_NODES);
    scan23_kernel<<<nn_blocks, 256, 0, stream>>>(rowp, bsums, N_NODES, N_EDGES);
    place_kernel<<<ne_blocks, 256, 0, stream>>>(ei, ew, rank, rowp, dis, pairs);

    int agg_blocks = (N_NODES * 16) / 256;   // 6250, exact

    // layer 1 aggregate: A1 = agg(xb) [bf16]
    aggregate_kernel<true><<<agg_blocks, 256, 0, stream>>>(
        (const uint4*)xb, rowp, pairs, A1, nullptr);

    // fused dense stack: t = relu(A1 @ W1 + b1) @ W2  [bf16]
    gemm_fused_kernel<<<(N_NODES + 127) / 128, 256, 0, stream>>>(
        A1, W1F, b1, W2F, t, N_NODES);

    // layer 2 aggregate: out = agg(t) + b2 [fp32]
    aggregate_kernel<false><<<agg_blocks, 256, 0, stream>>>(
        (const uint4*)t, rowp, pairs, out, b2);
}

// Round 4
// 274.562 us; speedup vs baseline: 1.1285x; 1.0094x over previous
//
#include <hip/hip_runtime.h>
#include <hip/hip_bf16.h>
#include <cstdint>
#include <cstddef>

#define N_NODES 100000
#define N_EDGES 800000
#define IN_DIM 128
#define HID_DIM 256
#define OUT_DIM 128

// deg fixed-point scale: 2^21. Max per-node wsum before low-word carry is
// 2^11 edges/node; random graph max-degree ~30. Per-edge quant error 2^-21.
#define DEG_SCALE 2097152.0f
#define DEG_INV   (1.0f / 2097152.0f)

typedef __attribute__((ext_vector_type(8))) short bf16x8;
typedef __attribute__((ext_vector_type(4))) float f32x4;

__device__ __forceinline__ unsigned short f32_to_bf16(float f) {
    __hip_bfloat16 b = __float2bfloat16(f);   // RNE
    return *reinterpret_cast<unsigned short*>(&b);
}
__device__ __forceinline__ float bf16_lo(uint32_t u) {
    uint32_t v = u << 16; return *reinterpret_cast<float*>(&v);
}
__device__ __forceinline__ float bf16_hi(uint32_t u) {
    uint32_t v = u & 0xffff0000u; return *reinterpret_cast<float*>(&v);
}

// ---------------------------------------------------------------------------
// Fused histogram + prep. Histogram is atomic-unit-bound (R1/R2 counters:
// VALUBusy ~2%, hbm ~22%) so prep blocks backfill and soak bandwidth.
// ONE u64 atomic per edge carries BOTH count (high word) and fixed-point
// weight sum (low word) -> deg/dis available at scan time, no extra passes.
// ---------------------------------------------------------------------------
#define HIST_BLOCKS 3125    // 3125*256 == 800000 exactly
#define XB_BLOCKS 12500     // 12500*256*4 == 100000*128

__global__ void hist_prep_kernel(const int* __restrict__ ei,
                                 const float* __restrict__ ew,
                                 unsigned long long* __restrict__ cnt64,
                                 int* __restrict__ rank,
                                 const float* __restrict__ x,
                                 uint32_t* __restrict__ xb,
                                 const float* __restrict__ W1,
                                 unsigned short* __restrict__ W1F,
                                 const float* __restrict__ W2,
                                 unsigned short* __restrict__ W2F) {
    int b = blockIdx.x;
    if (b < HIST_BLOCKS) {
        int e = b * 256 + threadIdx.x;
        int c = ei[N_EDGES + e];
        uint32_t wfix = (uint32_t)(ew[e] * DEG_SCALE + 0.5f);
        unsigned long long add = (1ULL << 32) | (unsigned long long)wfix;
        unsigned long long old = atomicAdd(&cnt64[c], add);
        rank[e] = (int)(old >> 32);
        return;
    }
    b -= HIST_BLOCKS;
    if (b < XB_BLOCKS) {                               // xb = bf16(x)
        int i = b * 256 + threadIdx.x;
        float4 v = ((const float4*)x)[i];
        uint32_t lo = (uint32_t)f32_to_bf16(v.x) | ((uint32_t)f32_to_bf16(v.y) << 16);
        uint32_t hi = (uint32_t)f32_to_bf16(v.z) | ((uint32_t)f32_to_bf16(v.w) << 16);
        ((uint2*)xb)[i] = make_uint2(lo, hi);
    } else if (b < XB_BLOCKS + 128) {                  // W1F: 32768 shorts
        int idx = (b - XB_BLOCKS) * 256 + threadIdx.x;
        int j = idx & 7, lane = (idx >> 3) & 63;
        int nt = (idx >> 9) & 3, ks = (idx >> 11) & 3;
        int wc = (idx >> 13) & 1, nh = (idx >> 14) & 1;
        int fr = lane & 15, fq = lane >> 4;
        int row = nh * 128 + wc * 64 + nt * 16 + fr;
        int kk = ks * 32 + fq * 8 + j;
        W1F[idx] = f32_to_bf16(W1[kk * HID_DIM + row]);
    } else {                                           // W2F: 32768 shorts
        int idx = (b - XB_BLOCKS - 128) * 256 + threadIdx.x;
        int j = idx & 7, lane = (idx >> 3) & 63;
        int nt = (idx >> 9) & 3, ks = (idx >> 11) & 3;
        int wc = (idx >> 13) & 1, nh = (idx >> 14) & 1;
        int fr = lane & 15, fq = lane >> 4;
        int n = wc * 64 + nt * 16 + fr;
        int kk = nh * 128 + ks * 32 + fq * 8 + j;
        W2F[idx] = f32_to_bf16(W2[kk * OUT_DIM + n]);
    }
}

// scan1: block-exclusive scan of counts (high words); also emits dis from
// the packed weight sums (low words).
__global__ void scan1_kernel(const unsigned long long* __restrict__ cnt64,
                             int* __restrict__ out, int* __restrict__ bsums,
                             float* __restrict__ dis, int n) {
    __shared__ int tmp[256];
    int t = threadIdx.x;
    int i = blockIdx.x * 256 + t;
    unsigned long long cv = (i < n) ? cnt64[i] : 0ULL;
    int v = (int)(cv >> 32);
    tmp[t] = v;
    __syncthreads();
    for (int off = 1; off < 256; off <<= 1) {
        int u = (t >= off) ? tmp[t - off] : 0;
        __syncthreads();
        tmp[t] += u;
        __syncthreads();
    }
    if (i < n) {
        out[i] = tmp[t] - v;                 // exclusive
        uint32_t wf = (uint32_t)cv;
        dis[i] = wf ? rsqrtf((float)wf * DEG_INV) : 0.f;
    }
    if (t == 255) bsums[blockIdx.x] = tmp[255];
}

// scan2+scan3 fused: each block reduces its own bsums prefix (<=391 ints).
__global__ void scan23_kernel(int* __restrict__ rowp, const int* __restrict__ bsums,
                              int n, int total) {
    __shared__ int red[256];
    int b = blockIdx.x, t = threadIdx.x;
    int s = 0;
    for (int i = t; i < b; i += 256) s += bsums[i];
    red[t] = s;
    __syncthreads();
    for (int off = 128; off > 0; off >>= 1) {
        if (t < off) red[t] += red[t + off];
        __syncthreads();
    }
    int pre = red[0];
    int i = b * 256 + t;
    if (i == 0) rowp[n] = total;
    if (i < n) rowp[i] += pre;
}

// place: no atomics — slot = rowp[col] + rank[e]. Writes the FULLY
// NORMALIZED weight (dis ready since scan1); both aggregates skip dis.
__global__ void place_kernel(const int* __restrict__ ei,
                             const float* __restrict__ ew,
                             const int* __restrict__ rank,
                             const int* __restrict__ rowp,
                             const float* __restrict__ dis,
                             int2* __restrict__ pairs) {
    int e = blockIdx.x * 256 + threadIdx.x;
    if (e >= N_EDGES) return;
    int s = ei[e];
    int c = ei[N_EDGES + e];
    int pos = rowp[c] + rank[e];
    float wn = ew[e] * dis[s] * dis[c];      // dis: 400KB, L2-resident
    pairs[pos] = make_int2(s, __float_as_int(wn));
}

// ---------------------------------------------------------------------------
// Aggregation R11: 4 nodes per wave (16 lanes/node, uint4 = 8 bf16/lane).
// The kernel is a dependent-epoch latency chain (R3 analysis: ~24 block
// rounds x ~1.7us of pairs->gather round trips; VALUBusy 32%, gather rate
// 1/115cyc/CU — nowhere near any throughput wall). Old tail handling
// (4-then-2-then-1) cost up to 3 extra sequential epochs per node.
// Now: ceil(deg/8) epochs total — full-8 epochs + ONE masked tail epoch
// (masked-4 when remainder<=4 to cap wasted gathers). Invalid slots clamp
// to pairs[beg] with weight forced to 0.
// ---------------------------------------------------------------------------
__device__ __forceinline__ void acc_edge(float w, uint4 u, float* a) {
    a[0] += w * bf16_lo(u.x); a[1] += w * bf16_hi(u.x);
    a[2] += w * bf16_lo(u.y); a[3] += w * bf16_hi(u.y);
    a[4] += w * bf16_lo(u.z); a[5] += w * bf16_hi(u.z);
    a[6] += w * bf16_lo(u.w); a[7] += w * bf16_hi(u.w);
}

template <bool OUT_BF16>
__global__ void aggregate_kernel(const uint4* __restrict__ feat,
                                 const int* __restrict__ rowp,
                                 const int2* __restrict__ pairs,
                                 void* __restrict__ out_v,
                                 const float* __restrict__ bias) {
    int gtid = blockIdx.x * blockDim.x + threadIdx.x;
    int node = gtid >> 4;
    int lane = threadIdx.x & 15;
    if (node >= N_NODES) return;
    int beg = rowp[node], end = rowp[node + 1];
    float a[8] = {};

    int j = beg;
    // full unmasked epochs
    for (; j + 8 <= end; j += 8) {
        int2 p[8]; uint4 u[8];
        #pragma unroll
        for (int q = 0; q < 8; ++q) p[q] = pairs[j + q];
        #pragma unroll
        for (int q = 0; q < 8; ++q) u[q] = feat[(size_t)p[q].x * 16 + lane];
        #pragma unroll
        for (int q = 0; q < 8; ++q) acc_edge(__int_as_float(p[q].y), u[q], a);
    }
    int r = end - j;
    if (r > 4) {
        // ONE masked epoch-8 (no sequential tail chain)
        int2 p[8]; uint4 u[8];
        #pragma unroll
        for (int q = 0; q < 8; ++q) {
            int idx = (j + q < end) ? j + q : beg;
            p[q] = pairs[idx];
        }
        #pragma unroll
        for (int q = 0; q < 8; ++q) u[q] = feat[(size_t)p[q].x * 16 + lane];
        #pragma unroll
        for (int q = 0; q < 8; ++q) {
            float w = (j + q < end) ? __int_as_float(p[q].y) : 0.f;
            acc_edge(w, u[q], a);
        }
    } else if (r > 0) {
        // ONE masked epoch-4
        int2 p[4]; uint4 u[4];
        #pragma unroll
        for (int q = 0; q < 4; ++q) {
            int idx = (j + q < end) ? j + q : beg;
            p[q] = pairs[idx];
        }
        #pragma unroll
        for (int q = 0; q < 4; ++q) u[q] = feat[(size_t)p[q].x * 16 + lane];
        #pragma unroll
        for (int q = 0; q < 4; ++q) {
            float w = (j + q < end) ? __int_as_float(p[q].y) : 0.f;
            acc_edge(w, u[q], a);
        }
    }

    if (bias) {
        float4 b0 = ((const float4*)bias)[lane * 2];
        float4 b1 = ((const float4*)bias)[lane * 2 + 1];
        a[0] += b0.x; a[1] += b0.y; a[2] += b0.z; a[3] += b0.w;
        a[4] += b1.x; a[5] += b1.y; a[6] += b1.z; a[7] += b1.w;
    }
    if (OUT_BF16) {
        uint4 o;
        o.x = (uint32_t)f32_to_bf16(a[0]) | ((uint32_t)f32_to_bf16(a[1]) << 16);
        o.y = (uint32_t)f32_to_bf16(a[2]) | ((uint32_t)f32_to_bf16(a[3]) << 16);
        o.z = (uint32_t)f32_to_bf16(a[4]) | ((uint32_t)f32_to_bf16(a[5]) << 16);
        o.w = (uint32_t)f32_to_bf16(a[6]) | ((uint32_t)f32_to_bf16(a[7]) << 16);
        ((uint4*)out_v)[(size_t)node * 16 + lane] = o;
    } else {
        ((float4*)out_v)[(size_t)node * 32 + lane * 2] =
            make_float4(a[0], a[1], a[2], a[3]);
        ((float4*)out_v)[(size_t)node * 32 + lane * 2 + 1] =
            make_float4(a[4], a[5], a[6], a[7]);
    }
}

// ---------------------------------------------------------------------------
// Fused 2-layer GEMM: T = relu(A @ W1 + b1) @ W2, bf16 in/out, fp32 acc.
// W streams are fragment-ordered (W1F/W2F) -> every wf load is one coalesced
// global_load_dwordx4; A-fragments hoisted to registers once (af[4][4]).
// LDS 66KB -> 2 blocks/CU; launch_bounds(256,2).
// ---------------------------------------------------------------------------
__global__ __launch_bounds__(256, 2) void gemm_fused_kernel(
    const unsigned short* __restrict__ A,     // [M][128] bf16
    const unsigned short* __restrict__ W1F,   // frag-ordered, 32768 shorts
    const float* __restrict__ b1,             // [256]
    const unsigned short* __restrict__ W2F,   // frag-ordered, 32768 shorts
    unsigned short* __restrict__ T,           // [M][128] bf16
    int M) {
    __shared__ unsigned short As[128 * 128];  // 32KB, chunk-swizzled
    __shared__ unsigned short Hs[128 * 136];  // 34KB, padded rows
    int tid = threadIdx.x;
    int wave = tid >> 6, lane = tid & 63;
    int m0 = blockIdx.x * 128;
    int wr = (wave & 1) * 64;
    int wcid = wave >> 1;
    int wc = wcid * 64;
    int fr = lane & 15, fq = lane >> 4;

    // stage A block: 2048 16B-chunks, 8 rounds of 256 lanes (XOR-swizzled)
    #pragma unroll
    for (int i = 0; i < 8; ++i) {
        int cbase = (i * 4 + wave) * 64;
        int c = cbase + lane;
        int m = c >> 4, cl = c & 15;
        int qg = ((cl & 7) ^ (m & 7)) | (cl & 8);
        int gm = m0 + m; if (gm >= M) gm = M - 1;
        const unsigned short* ga = A + (size_t)gm * 128 + qg * 8;
        __builtin_amdgcn_global_load_lds(
            (const __attribute__((address_space(1))) void*)ga,
            (__attribute__((address_space(3))) void*)(As + (size_t)cbase * 8),
            16, 0, 0);
    }
    __syncthreads();

    // A fragments to registers once; reused by both nh halves.
    bf16x8 af[4][4];   // [ks][mt]
    #pragma unroll
    for (int ks = 0; ks < 4; ++ks) {
        int q = ks * 4 + fq;
        int cl = ((q & 7) ^ (fr & 7)) | (q & 8);
        #pragma unroll
        for (int mt = 0; mt < 4; ++mt)
            af[ks][mt] = *(const bf16x8*)(As + (wr + mt * 16 + fr) * 128 + cl * 8);
    }

    const bf16x8* w1p = (const bf16x8*)W1F;
    const bf16x8* w2p = (const bf16x8*)W2F;

    f32x4 acc_t[4][4] = {};
    #pragma unroll
    for (int nh = 0; nh < 2; ++nh) {
        int wbase = (nh * 2 + wcid) * 16 * 64;   // 16 frags x 64 lanes per (nh,wc)
        // phase A: acc_h = A_tile @ W1[nh half]
        f32x4 acc_h[4][4] = {};
        #pragma unroll
        for (int ks = 0; ks < 4; ++ks) {
            bf16x8 wf[4];
            #pragma unroll
            for (int nt = 0; nt < 4; ++nt)
                wf[nt] = w1p[wbase + (ks * 4 + nt) * 64 + lane];
            #pragma unroll
            for (int mt = 0; mt < 4; ++mt)
                #pragma unroll
                for (int nt = 0; nt < 4; ++nt)
                    acc_h[mt][nt] = __builtin_amdgcn_mfma_f32_16x16x32_bf16(
                        af[ks][mt], wf[nt], acc_h[mt][nt], 0, 0, 0);
        }
        float bv[4];
        #pragma unroll
        for (int nt = 0; nt < 4; ++nt) bv[nt] = b1[nh * 128 + wc + nt * 16 + fr];
        __syncthreads();   // prior half's Hs consumers done
        #pragma unroll
        for (int mt = 0; mt < 4; ++mt)
            #pragma unroll
            for (int r = 0; r < 4; ++r) {
                int row = wr + mt * 16 + fq * 4 + r;
                #pragma unroll
                for (int nt = 0; nt < 4; ++nt) {
                    float v = fmaxf(acc_h[mt][nt][r] + bv[nt], 0.f);
                    Hs[row * 136 + wc + nt * 16 + fr] = f32_to_bf16(v);
                }
            }
        __syncthreads();   // Hs ready
        // phase B: acc_t += Hs @ W2[nh half rows]
        #pragma unroll
        for (int ks = 0; ks < 4; ++ks) {
            bf16x8 wf[4], hf[4];
            #pragma unroll
            for (int nt = 0; nt < 4; ++nt)
                wf[nt] = w2p[wbase + (ks * 4 + nt) * 64 + lane];
            #pragma unroll
            for (int mt = 0; mt < 4; ++mt)
                hf[mt] = *(const bf16x8*)(Hs + (wr + mt * 16 + fr) * 136 + ks * 32 + fq * 8);
            #pragma unroll
            for (int mt = 0; mt < 4; ++mt)
                #pragma unroll
                for (int nt = 0; nt < 4; ++nt)
                    acc_t[mt][nt] = __builtin_amdgcn_mfma_f32_16x16x32_bf16(
                        hf[mt], wf[nt], acc_t[mt][nt], 0, 0, 0);
        }
    }

    // epilogue: C/D layout col=lane&15, row=(lane>>4)*4+reg (m89-verified)
    #pragma unroll
    for (int mt = 0; mt < 4; ++mt)
        #pragma unroll
        for (int r = 0; r < 4; ++r) {
            int row = m0 + wr + mt * 16 + fq * 4 + r;
            if (row >= M) continue;
            #pragma unroll
            for (int nt = 0; nt < 4; ++nt)
                T[(size_t)row * 128 + wc + nt * 16 + fr] = f32_to_bf16(acc_t[mt][nt][r]);
        }
}

// ---------------------------------------------------------------------------
extern "C" void kernel_launch(void* const* d_in, const int* in_sizes, int n_in,
                              void* d_out, int out_size, void* d_ws, size_t ws_size,
                              hipStream_t stream) {
    const float* x  = (const float*)d_in[0];
    const int*   ei = (const int*)d_in[1];    // int32 (harness converts ints)
    const float* ew = (const float*)d_in[2];
    const float* W1 = (const float*)d_in[3];
    const float* b1 = (const float*)d_in[4];
    const float* W2 = (const float*)d_in[5];
    const float* b2 = (const float*)d_in[6];
    float* out = (float*)d_out;

    char* ws = (char*)d_ws;
    size_t off = 0;
    auto alloc = [&](size_t bytes) -> void* {
        void* p = ws + off;
        off = (off + bytes + 255) & ~(size_t)255;
        return p;
    };
    unsigned long long* cnt64 = (unsigned long long*)alloc((size_t)N_NODES * 8);
    float* dis   = (float*)alloc((size_t)N_NODES * 4);
    int*   rowp  = (int*)  alloc((size_t)(N_NODES + 1) * 4);
    int*   bsums = (int*)  alloc(512 * 4);
    int*   rank  = (int*)  alloc((size_t)N_EDGES * 4);
    int2*  pairs = (int2*) alloc((size_t)N_EDGES * 8);
    uint32_t* xb = (uint32_t*)alloc((size_t)N_NODES * IN_DIM * 2);
    unsigned short* W1F = (unsigned short*)alloc((size_t)IN_DIM * HID_DIM * 2);
    unsigned short* W2F = (unsigned short*)alloc((size_t)HID_DIM * OUT_DIM * 2);
    unsigned short* A1  = (unsigned short*)alloc((size_t)N_NODES * IN_DIM * 2);
    unsigned short* t   = (unsigned short*)alloc((size_t)N_NODES * OUT_DIM * 2);

    hipMemsetAsync(cnt64, 0, (size_t)N_NODES * 8, stream);

    int nn_blocks = (N_NODES + 255) / 256;   // 391
    int ne_blocks = (N_EDGES + 255) / 256;   // 3125

    // fused: histogram (atomic-unit-bound) overlapped with prep (BW-bound)
    hist_prep_kernel<<<HIST_BLOCKS + XB_BLOCKS + 256, 256, 0, stream>>>(
        ei, ew, cnt64, rank, x, xb, W1, W1F, W2, W2F);

    scan1_kernel<<<nn_blocks, 256, 0, stream>>>(cnt64, rowp, bsums, dis, N_NODES);
    scan23_kernel<<<nn_blocks, 256, 0, stream>>>(rowp, bsums, N_NODES, N_EDGES);
    place_kernel<<<ne_blocks, 256, 0, stream>>>(ei, ew, rank, rowp, dis, pairs);

    int agg_blocks = (N_NODES * 16) / 256;   // 6250, exact

    // layer 1 aggregate: A1 = agg(xb) [bf16]
    aggregate_kernel<true><<<agg_blocks, 256, 0, stream>>>(
        (const uint4*)xb, rowp, pairs, A1, nullptr);

    // fused dense stack: t = relu(A1 @ W1 + b1) @ W2  [bf16]
    gemm_fused_kernel<<<(N_NODES + 127) / 128, 256, 0, stream>>>(
        A1, W1F, b1, W2F, t, N_NODES);

    // layer 2 aggregate: out = agg(t) + b2 [fp32]
    aggregate_kernel<false><<<agg_blocks, 256, 0, stream>>>(
        (const uint4*)t, rowp, pairs, out, b2);
}